// Round 14
// baseline (143.856 us; speedup 1.0000x reference)
//
#include <hip/hip_runtime.h>
#include <hip/hip_fp16.h>

// GCN: 3x GCNConv (11->32->64->128) + mean-pool + MLP (128->64->12)
// N=50000, E=600000, G=512. Multi-kernel graph.
// Lessons: R8 persistent mega-kernel (software grid barriers) 148->658us;
// R10 last-block election w/ agent-scope fences: prep 12->107us (L2 wb/inv);
// R11 split-pool: +1 launch + 2x index traffic, net loss.
// R13: __builtin_nontemporal_load rejects HIP float4* — dropped.
// - aggregate-before-GEMM (widths 16(pad)/32/64), pool-before-GEMM for L3
// - on-device CSR; counts from scan diffs; atomicSub claims slots
// - fp16 intermediates incl. hx; 8-wide gather unroll (2 acc banks x 4 loads)

#define GG 512
#define TGT 12

union F4H8 { float4 f4; __half2 h2[4]; };
union F2H4 { float2 f2; __half2 h2[2]; };

__device__ __forceinline__ void acc_add_h8(float* a, float4 raw) {
    F4H8 u; u.f4 = raw;
#pragma unroll
    for (int k = 0; k < 4; ++k) {
        float2 f = __half22float2(u.h2[k]);
        a[2 * k] += f.x;
        a[2 * k + 1] += f.y;
    }
}

__device__ __forceinline__ void acc_add_h4(float* a, float2 raw) {
    F2H4 u; u.f2 = raw;
#pragma unroll
    for (int k = 0; k < 2; ++k) {
        float2 f = __half22float2(u.h2[k]);
        a[2 * k] += f.x;
        a[2 * k + 1] += f.y;
    }
}

__global__ void zero_kernel(int4* __restrict__ p, int n4) {
    int i = blockIdx.x * blockDim.x + threadIdx.x;
    if (i < n4) p[i] = make_int4(0, 0, 0, 0);
}

__global__ void deg_count_kernel(const int* __restrict__ dst, int* __restrict__ cnt, int E) {
    int i = blockIdx.x * blockDim.x + threadIdx.x;
    if (i < E) atomicAdd(&cnt[dst[i]], 1);
}

// ---- fused: dis + scaled/padded x (fp16) + zero pooled + per-chunk scan ----

__global__ void prep_kernel(const int* __restrict__ cnt, const float* __restrict__ x,
                            float* __restrict__ dis, __half* __restrict__ hx,
                            float* __restrict__ pooled,
                            int* __restrict__ excl, int* __restrict__ psum, int n, int nb1) {
    int gid = blockIdx.x * 256 + threadIdx.x;
    int gstride = gridDim.x * 256;
    for (int idx = gid; idx < n * 16; idx += gstride) {
        int node = idx >> 4, lane = idx & 15;
        float d = rsqrtf(1.0f + (float)cnt[node]);
        if (lane == 0) dis[node] = d;
        hx[idx] = __float2half((lane < 11) ? x[node * 11 + lane] * d : 0.0f);
    }
    for (int idx = gid; idx < GG * 64; idx += gstride) pooled[idx] = 0.0f;
    if ((int)blockIdx.x < nb1) {
        __shared__ int sh[256];
        int i = blockIdx.x * 256 + threadIdx.x;
        int v = (i < n) ? cnt[i] : 0;
        sh[threadIdx.x] = v;
        __syncthreads();
        for (int off = 1; off < 256; off <<= 1) {
            int t = (threadIdx.x >= (unsigned)off) ? sh[threadIdx.x - off] : 0;
            __syncthreads();
            sh[threadIdx.x] += t;
            __syncthreads();
        }
        if (i < n) excl[i] = sh[threadIdx.x] - v;
        if (threadIdx.x == 255) psum[blockIdx.x] = sh[255];
    }
}

__global__ void scan2_kernel(int* __restrict__ psum, int nb) {
    __shared__ int sh[256];
    int carry = 0;
    for (int base = 0; base < nb; base += 256) {
        int i = base + threadIdx.x;
        int v = (i < nb) ? psum[i] : 0;
        sh[threadIdx.x] = v;
        __syncthreads();
        for (int off = 1; off < 256; off <<= 1) {
            int t = (threadIdx.x >= (unsigned)off) ? sh[threadIdx.x - off] : 0;
            __syncthreads();
            sh[threadIdx.x] += t;
            __syncthreads();
        }
        if (i < nb) psum[i] = sh[threadIdx.x] - v + carry;
        carry += sh[255];
        __syncthreads();
    }
}

__global__ void place_kernel(const int* __restrict__ src, const int* __restrict__ dst,
                             const int* __restrict__ excl, const int* __restrict__ psum,
                             int* __restrict__ incnt, int* __restrict__ esrc, int E) {
    int i = blockIdx.x * blockDim.x + threadIdx.x;
    if (i < E) {
        int d = dst[i];
        int r = atomicSub(&incnt[d], 1) - 1;
        esrc[excl[d] + psum[d >> 8] + r] = src[i];
    }
}

__device__ __forceinline__ int offs_of(const int* __restrict__ excl,
                                       const int* __restrict__ psum, int i) {
    return excl[i] + psum[i >> 8];
}

// ---- layer 1: fp16 gather (width 16 halves, 4 lanes/node x 8B) + GEMM 11->32 ----

__global__ void aggemm1_kernel(const float2* __restrict__ hp, const float* __restrict__ dis,
                               const int* __restrict__ excl, const int* __restrict__ psum,
                               const int* __restrict__ esrc,
                               const float* __restrict__ W, const float* __restrict__ b,
                               __half* __restrict__ out, int n, int Etot) {
    __shared__ float srow[64 * 16];
    __shared__ float sdn[64];
    __shared__ float sW[11 * 32];
    for (int i = threadIdx.x; i < 11 * 32; i += 256) sW[i] = W[i];

    int nd = threadIdx.x >> 2, lane = threadIdx.x & 3;
    int node = blockIdx.x * 64 + nd;
    if (node < n) {
        int s0 = offs_of(excl, psum, node);
        int send = (node + 1 < n) ? offs_of(excl, psum, node + 1) : Etot;
        int c = send - s0;
        float accA[4] = {0, 0, 0, 0};
        float accB[4] = {0, 0, 0, 0};
        acc_add_h4(accA, hp[(size_t)node * 4 + lane]);
        int e = 0;
        for (; e + 8 <= c; e += 8) {
            int s_[8];
#pragma unroll
            for (int k = 0; k < 8; ++k) s_[k] = esrc[s0 + e + k];
#pragma unroll
            for (int k = 0; k < 8; k += 2) {
                acc_add_h4(accA, hp[(size_t)s_[k] * 4 + lane]);
                acc_add_h4(accB, hp[(size_t)s_[k + 1] * 4 + lane]);
            }
        }
        for (; e < c; ++e) acc_add_h4(accA, hp[(size_t)esrc[s0 + e] * 4 + lane]);
        float dn = dis[node];
#pragma unroll
        for (int j = 0; j < 4; ++j) srow[nd * 16 + lane * 4 + j] = (accA[j] + accB[j]) * dn;
        if (lane == 0) sdn[nd] = dn;
    }
    __syncthreads();

    int base = blockIdx.x * 64;
    for (int o = threadIdx.x; o < 64 * 32; o += 256) {
        int fo = o & 31, nd2 = o >> 5;
        int node2 = base + nd2;
        if (node2 < n) {
            float a = b[fo];
#pragma unroll
            for (int fi = 0; fi < 11; ++fi) a += srow[nd2 * 16 + fi] * sW[fi * 32 + fo];
            out[(size_t)node2 * 32 + fo] = __float2half(fmaxf(a, 0.0f) * sdn[nd2]);
        }
    }
}

// ---- layer 2: fp16 gather (width 32 halves, 4 lanes/node x 16B) + GEMM 32->64 ----

__global__ void aggemm2_kernel(const float4* __restrict__ hp, const float* __restrict__ dis,
                               const int* __restrict__ excl, const int* __restrict__ psum,
                               const int* __restrict__ esrc,
                               const float* __restrict__ W, const float* __restrict__ b,
                               __half* __restrict__ out, int n, int Etot) {
    __shared__ float srow[64 * 32];
    __shared__ float sdn[64];
    __shared__ float sW[32 * 64];
    for (int i = threadIdx.x; i < 32 * 64; i += 256) sW[i] = W[i];

    int nd = threadIdx.x >> 2, lane = threadIdx.x & 3;
    int node = blockIdx.x * 64 + nd;
    if (node < n) {
        int s0 = offs_of(excl, psum, node);
        int send = (node + 1 < n) ? offs_of(excl, psum, node + 1) : Etot;
        int c = send - s0;
        float accA[8] = {0, 0, 0, 0, 0, 0, 0, 0};
        float accB[8] = {0, 0, 0, 0, 0, 0, 0, 0};
        acc_add_h8(accA, hp[(size_t)node * 4 + lane]);
        int e = 0;
        for (; e + 8 <= c; e += 8) {
            int s_[8];
#pragma unroll
            for (int k = 0; k < 8; ++k) s_[k] = esrc[s0 + e + k];
#pragma unroll
            for (int k = 0; k < 8; k += 2) {
                acc_add_h8(accA, hp[(size_t)s_[k] * 4 + lane]);
                acc_add_h8(accB, hp[(size_t)s_[k + 1] * 4 + lane]);
            }
        }
        for (; e < c; ++e) acc_add_h8(accA, hp[(size_t)esrc[s0 + e] * 4 + lane]);
        float dn = dis[node];
#pragma unroll
        for (int j = 0; j < 8; ++j) srow[nd * 32 + lane * 8 + j] = (accA[j] + accB[j]) * dn;
        if (lane == 0) sdn[nd] = dn;
    }
    __syncthreads();

    int base = blockIdx.x * 64;
    for (int o = threadIdx.x; o < 64 * 64; o += 256) {
        int fo = o & 63, nd2 = o >> 6;
        int node2 = base + nd2;
        if (node2 < n) {
            float a = b[fo];
#pragma unroll
            for (int fi = 0; fi < 32; ++fi) a += srow[nd2 * 32 + fi] * sW[fi * 64 + fo];
            out[(size_t)node2 * 64 + fo] = __float2half(fmaxf(a, 0.0f) * sdn[nd2]);
        }
    }
}

// ---- layer 3: fp16 gather (width 64 halves, 8 lanes/node x 16B) + segmented mean-pool ----

__global__ void agg64pool_kernel(const float4* __restrict__ hp, const float* __restrict__ dis,
                                 const int* __restrict__ excl, const int* __restrict__ psum,
                                 const int* __restrict__ esrc, const int* __restrict__ batch,
                                 float* __restrict__ pooled, int n, int Etot) {
    __shared__ float srow[32 * 64];
    int nd = threadIdx.x >> 3, lane = threadIdx.x & 7;
    int base = blockIdx.x * 32;
    int node = base + nd;
    if (node < n) {
        int s0 = offs_of(excl, psum, node);
        int send = (node + 1 < n) ? offs_of(excl, psum, node + 1) : Etot;
        int c = send - s0;
        float accA[8] = {0, 0, 0, 0, 0, 0, 0, 0};
        float accB[8] = {0, 0, 0, 0, 0, 0, 0, 0};
        acc_add_h8(accA, hp[(size_t)node * 8 + lane]);
        int e = 0;
        for (; e + 8 <= c; e += 8) {
            int s_[8];
#pragma unroll
            for (int k = 0; k < 8; ++k) s_[k] = esrc[s0 + e + k];
#pragma unroll
            for (int k = 0; k < 8; k += 2) {
                acc_add_h8(accA, hp[(size_t)s_[k] * 8 + lane]);
                acc_add_h8(accB, hp[(size_t)s_[k + 1] * 8 + lane]);
            }
        }
        for (; e < c; ++e) acc_add_h8(accA, hp[(size_t)esrc[s0 + e] * 8 + lane]);
        float dn = dis[node];
#pragma unroll
        for (int j = 0; j < 8; ++j) srow[nd * 64 + lane * 8 + j] = (accA[j] + accB[j]) * dn;
    } else {
#pragma unroll
        for (int j = 0; j < 8; ++j) srow[nd * 64 + lane * 8 + j] = 0.0f;
    }
    __syncthreads();

    // quarter q handles nodes q*8..q*8+7: register run over sorted batch, flush on change
    int fo = threadIdx.x & 63, q = threadIdx.x >> 6;
    float acc = 0.0f;
    int gcur = -1;
    for (int k = 0; k < 8; ++k) {
        int node2 = base + q * 8 + k;
        if (node2 >= n) break;
        int g = batch[node2];
        if (g != gcur) {
            if (gcur >= 0) atomicAdd(&pooled[(size_t)gcur * 64 + fo], acc);
            acc = 0.0f;
            gcur = g;
        }
        acc += srow[(q * 8 + k) * 64 + fo];
    }
    if (gcur >= 0) atomicAdd(&pooled[(size_t)gcur * 64 + fo], acc);
}

// ---- head per graph: p128=(pooled/c)@W3+b3; h64=relu(p128@fw1+fb1); out=h64@fw2+fb2 ----

__global__ void head_kernel(const float* __restrict__ pooled, const int* __restrict__ batch,
                            const float* __restrict__ W3, const float* __restrict__ b3,
                            const float* __restrict__ fw1, const float* __restrict__ fb1,
                            const float* __restrict__ fw2, const float* __restrict__ fb2,
                            float* __restrict__ out, int n) {
    int g = blockIdx.x;
    auto lb = [&](int key) {
        int lo = 0, hi = n;
        while (lo < hi) {
            int mid = (lo + hi) >> 1;
            if (batch[mid] < key) lo = mid + 1; else hi = mid;
        }
        return lo;
    };
    int lo = lb(g), hi = lb(g + 1);
    float c = (float)(hi - lo);
    float inv = (c > 0.0f) ? 1.0f / c : 0.0f;

    __shared__ float sp[64];
    __shared__ float p128[128];
    __shared__ float h64[64];
    int j = threadIdx.x;  // 0..127
    if (j < 64) sp[j] = pooled[(size_t)g * 64 + j] * inv;
    __syncthreads();
    {
        float a = (c > 0.0f) ? b3[j] : 0.0f;  // empty graph: reference pooled128 = 0
#pragma unroll
        for (int k = 0; k < 64; ++k) a += sp[k] * W3[k * 128 + j];
        p128[j] = a;
    }
    __syncthreads();
    if (j < 64) {
        float a = fb1[j];
#pragma unroll
        for (int k = 0; k < 128; ++k) a += p128[k] * fw1[k * 64 + j];
        h64[j] = fmaxf(a, 0.0f);
    }
    __syncthreads();
    if (j < TGT) {
        float a = fb2[j];
#pragma unroll
        for (int k = 0; k < 64; ++k) a += h64[k] * fw2[k * TGT + j];
        out[(size_t)g * TGT + j] = a;
    }
}

extern "C" void kernel_launch(void* const* d_in, const int* in_sizes, int n_in,
                              void* d_out, int out_size, void* d_ws, size_t ws_size,
                              hipStream_t stream) {
    const float* x = (const float*)d_in[0];
    const int* edge_index = (const int*)d_in[1];
    const int* batch = (const int*)d_in[2];
    const float* W1 = (const float*)d_in[3];
    const float* b1 = (const float*)d_in[4];
    const float* W2 = (const float*)d_in[5];
    const float* b2 = (const float*)d_in[6];
    const float* W3 = (const float*)d_in[7];
    const float* b3 = (const float*)d_in[8];
    const float* fw1 = (const float*)d_in[9];
    const float* fb1 = (const float*)d_in[10];
    const float* fw2 = (const float*)d_in[11];
    const float* fb2 = (const float*)d_in[12];
    float* out = (float*)d_out;

    const int N = in_sizes[2];
    const int E = in_sizes[1] / 2;
    const int* src = edge_index;
    const int* dst = edge_index + E;

    // workspace
    int* incnt = (int*)d_ws;                        // N (zeroed; consumed by place)
    float* pooled = (float*)(incnt + N);            // GG*64 (zeroed by prep)
    int* excl = (int*)(pooled + GG * 64);           // N
    int* psum = excl + N;                           // 256
    int* esrc = psum + 256;                         // E
    float* dis = (float*)(esrc + E);                // N
    __half* hx = (__half*)(dis + N);                // N*16 halves
    __half* h1 = hx + (size_t)N * 16;               // N*32 halves
    __half* h2 = h1 + (size_t)N * 32;               // N*64 halves

    const int T = 256;
    auto cdiv = [](long long a, long long b) { return (int)((a + b - 1) / b); };
    const int nb1 = cdiv(N, 256);

    // ---- CSR build ----
    zero_kernel<<<cdiv(cdiv(N, 4), T), T, 0, stream>>>((int4*)incnt, cdiv(N, 4));
    deg_count_kernel<<<cdiv(E, T), T, 0, stream>>>(dst, incnt, E);
    prep_kernel<<<cdiv((long long)N * 16, T), T, 0, stream>>>(incnt, x, dis, hx, pooled,
                                                              excl, psum, N, nb1);
    scan2_kernel<<<1, 256, 0, stream>>>(psum, nb1);
    place_kernel<<<cdiv(E, T), T, 0, stream>>>(src, dst, excl, psum, incnt, esrc, E);

    // ---- layers ----
    aggemm1_kernel<<<cdiv(N, 64), T, 0, stream>>>(
        (const float2*)hx, dis, excl, psum, esrc, W1, b1, h1, N, E);
    aggemm2_kernel<<<cdiv(N, 64), T, 0, stream>>>(
        (const float4*)h1, dis, excl, psum, esrc, W2, b2, h2, N, E);
    agg64pool_kernel<<<cdiv(N, 32), T, 0, stream>>>(
        (const float4*)h2, dis, excl, psum, esrc, batch, pooled, N, E);
    head_kernel<<<GG, 128, 0, stream>>>(pooled, batch, W3, b3, fw1, fb1, fw2, fb2, out, N);
}

// Round 15
// 135.887 us; speedup vs baseline: 1.0586x; 1.0586x over previous
//
#include <hip/hip_runtime.h>
#include <hip/hip_fp16.h>

// GCN: 3x GCNConv (11->32->64->128) + mean-pool + MLP (128->64->12)
// N=50000, E=600000, G=512. Multi-kernel graph. BEST CONFIG (R12, 136us).
// Lessons: R8 persistent mega-kernel (software grid barriers) 148->658us;
// R10 last-block election w/ agent-scope fences: prep 12->107us (L2 wb/inv);
// R11 split-pool: +1 launch + 2x index traffic, net loss;
// R14 8-wide gather unroll: mean degree 12 -> longer serial tail, 136->144us.
// - aggregate-before-GEMM (widths 16(pad)/32/64), pool-before-GEMM for L3
// - on-device CSR; counts from scan diffs; atomicSub claims slots
// - fp16 intermediates incl. hx; 4-wide gather unroll (2 acc banks x 2 loads)

#define GG 512
#define TGT 12

union F4H8 { float4 f4; __half2 h2[4]; };
union F2H4 { float2 f2; __half2 h2[2]; };

__device__ __forceinline__ void acc_add_h8(float* a, float4 raw) {
    F4H8 u; u.f4 = raw;
#pragma unroll
    for (int k = 0; k < 4; ++k) {
        float2 f = __half22float2(u.h2[k]);
        a[2 * k] += f.x;
        a[2 * k + 1] += f.y;
    }
}

__device__ __forceinline__ void acc_add_h4(float* a, float2 raw) {
    F2H4 u; u.f2 = raw;
#pragma unroll
    for (int k = 0; k < 2; ++k) {
        float2 f = __half22float2(u.h2[k]);
        a[2 * k] += f.x;
        a[2 * k + 1] += f.y;
    }
}

__global__ void zero_kernel(int4* __restrict__ p, int n4) {
    int i = blockIdx.x * blockDim.x + threadIdx.x;
    if (i < n4) p[i] = make_int4(0, 0, 0, 0);
}

__global__ void deg_count_kernel(const int* __restrict__ dst, int* __restrict__ cnt, int E) {
    int i = blockIdx.x * blockDim.x + threadIdx.x;
    if (i < E) atomicAdd(&cnt[dst[i]], 1);
}

// ---- fused: dis + scaled/padded x (fp16) + per-chunk exclusive scan ----

__global__ void prep_kernel(const int* __restrict__ cnt, const float* __restrict__ x,
                            float* __restrict__ dis, __half* __restrict__ hx,
                            int* __restrict__ excl, int* __restrict__ psum, int n, int nb1) {
    int gid = blockIdx.x * 256 + threadIdx.x;
    int gstride = gridDim.x * 256;
    for (int idx = gid; idx < n * 16; idx += gstride) {
        int node = idx >> 4, lane = idx & 15;
        float d = rsqrtf(1.0f + (float)cnt[node]);
        if (lane == 0) dis[node] = d;
        hx[idx] = __float2half((lane < 11) ? x[node * 11 + lane] * d : 0.0f);
    }
    if ((int)blockIdx.x < nb1) {
        __shared__ int sh[256];
        int i = blockIdx.x * 256 + threadIdx.x;
        int v = (i < n) ? cnt[i] : 0;
        sh[threadIdx.x] = v;
        __syncthreads();
        for (int off = 1; off < 256; off <<= 1) {
            int t = (threadIdx.x >= (unsigned)off) ? sh[threadIdx.x - off] : 0;
            __syncthreads();
            sh[threadIdx.x] += t;
            __syncthreads();
        }
        if (i < n) excl[i] = sh[threadIdx.x] - v;
        if (threadIdx.x == 255) psum[blockIdx.x] = sh[255];
    }
}

__global__ void scan2_kernel(int* __restrict__ psum, int nb) {
    __shared__ int sh[256];
    int carry = 0;
    for (int base = 0; base < nb; base += 256) {
        int i = base + threadIdx.x;
        int v = (i < nb) ? psum[i] : 0;
        sh[threadIdx.x] = v;
        __syncthreads();
        for (int off = 1; off < 256; off <<= 1) {
            int t = (threadIdx.x >= (unsigned)off) ? sh[threadIdx.x - off] : 0;
            __syncthreads();
            sh[threadIdx.x] += t;
            __syncthreads();
        }
        if (i < nb) psum[i] = sh[threadIdx.x] - v + carry;
        carry += sh[255];
        __syncthreads();
    }
}

__global__ void place_kernel(const int* __restrict__ src, const int* __restrict__ dst,
                             const int* __restrict__ excl, const int* __restrict__ psum,
                             int* __restrict__ incnt, int* __restrict__ esrc, int E) {
    int i = blockIdx.x * blockDim.x + threadIdx.x;
    if (i < E) {
        int d = dst[i];
        int r = atomicSub(&incnt[d], 1) - 1;
        esrc[excl[d] + psum[d >> 8] + r] = src[i];
    }
}

__device__ __forceinline__ int offs_of(const int* __restrict__ excl,
                                       const int* __restrict__ psum, int i) {
    return excl[i] + psum[i >> 8];
}

// ---- layer 1: fp16 gather (width 16 halves, 4 lanes/node x 8B) + GEMM 11->32 ----

__global__ void aggemm1_kernel(const float2* __restrict__ hp, const float* __restrict__ dis,
                               const int* __restrict__ excl, const int* __restrict__ psum,
                               const int* __restrict__ esrc,
                               const float* __restrict__ W, const float* __restrict__ b,
                               __half* __restrict__ out, int n, int Etot) {
    __shared__ float srow[64 * 16];
    __shared__ float sdn[64];
    __shared__ float sW[11 * 32];
    for (int i = threadIdx.x; i < 11 * 32; i += 256) sW[i] = W[i];

    int nd = threadIdx.x >> 2, lane = threadIdx.x & 3;
    int node = blockIdx.x * 64 + nd;
    if (node < n) {
        int s0 = offs_of(excl, psum, node);
        int send = (node + 1 < n) ? offs_of(excl, psum, node + 1) : Etot;
        int c = send - s0;
        float accA[4] = {0, 0, 0, 0};
        float accB[4] = {0, 0, 0, 0};
        acc_add_h4(accA, hp[(size_t)node * 4 + lane]);
        int e = 0;
        for (; e + 4 <= c; e += 4) {
            int sa = esrc[s0 + e], sb = esrc[s0 + e + 1];
            int sc = esrc[s0 + e + 2], sd = esrc[s0 + e + 3];
            float2 va = hp[(size_t)sa * 4 + lane], vb = hp[(size_t)sb * 4 + lane];
            float2 vc = hp[(size_t)sc * 4 + lane], vd = hp[(size_t)sd * 4 + lane];
            acc_add_h4(accA, va); acc_add_h4(accB, vb);
            acc_add_h4(accA, vc); acc_add_h4(accB, vd);
        }
        for (; e < c; ++e) acc_add_h4(accA, hp[(size_t)esrc[s0 + e] * 4 + lane]);
        float dn = dis[node];
#pragma unroll
        for (int j = 0; j < 4; ++j) srow[nd * 16 + lane * 4 + j] = (accA[j] + accB[j]) * dn;
        if (lane == 0) sdn[nd] = dn;
    }
    __syncthreads();

    int base = blockIdx.x * 64;
    for (int o = threadIdx.x; o < 64 * 32; o += 256) {
        int fo = o & 31, nd2 = o >> 5;
        int node2 = base + nd2;
        if (node2 < n) {
            float a = b[fo];
#pragma unroll
            for (int fi = 0; fi < 11; ++fi) a += srow[nd2 * 16 + fi] * sW[fi * 32 + fo];
            out[(size_t)node2 * 32 + fo] = __float2half(fmaxf(a, 0.0f) * sdn[nd2]);
        }
    }
}

// ---- layer 2: fp16 gather (width 32 halves, 4 lanes/node x 16B) + GEMM 32->64 ----

__global__ void aggemm2_kernel(const float4* __restrict__ hp, const float* __restrict__ dis,
                               const int* __restrict__ excl, const int* __restrict__ psum,
                               const int* __restrict__ esrc,
                               const float* __restrict__ W, const float* __restrict__ b,
                               __half* __restrict__ out, int n, int Etot) {
    __shared__ float srow[64 * 32];
    __shared__ float sdn[64];
    __shared__ float sW[32 * 64];
    for (int i = threadIdx.x; i < 32 * 64; i += 256) sW[i] = W[i];

    int nd = threadIdx.x >> 2, lane = threadIdx.x & 3;
    int node = blockIdx.x * 64 + nd;
    if (node < n) {
        int s0 = offs_of(excl, psum, node);
        int send = (node + 1 < n) ? offs_of(excl, psum, node + 1) : Etot;
        int c = send - s0;
        float accA[8] = {0, 0, 0, 0, 0, 0, 0, 0};
        float accB[8] = {0, 0, 0, 0, 0, 0, 0, 0};
        acc_add_h8(accA, hp[(size_t)node * 4 + lane]);
        int e = 0;
        for (; e + 4 <= c; e += 4) {
            int sa = esrc[s0 + e], sb = esrc[s0 + e + 1];
            int sc = esrc[s0 + e + 2], sd = esrc[s0 + e + 3];
            float4 va = hp[(size_t)sa * 4 + lane], vb = hp[(size_t)sb * 4 + lane];
            float4 vc = hp[(size_t)sc * 4 + lane], vd = hp[(size_t)sd * 4 + lane];
            acc_add_h8(accA, va); acc_add_h8(accB, vb);
            acc_add_h8(accA, vc); acc_add_h8(accB, vd);
        }
        for (; e < c; ++e) acc_add_h8(accA, hp[(size_t)esrc[s0 + e] * 4 + lane]);
        float dn = dis[node];
#pragma unroll
        for (int j = 0; j < 8; ++j) srow[nd * 32 + lane * 8 + j] = (accA[j] + accB[j]) * dn;
        if (lane == 0) sdn[nd] = dn;
    }
    __syncthreads();

    int base = blockIdx.x * 64;
    for (int o = threadIdx.x; o < 64 * 64; o += 256) {
        int fo = o & 63, nd2 = o >> 6;
        int node2 = base + nd2;
        if (node2 < n) {
            float a = b[fo];
#pragma unroll
            for (int fi = 0; fi < 32; ++fi) a += srow[nd2 * 32 + fi] * sW[fi * 64 + fo];
            out[(size_t)node2 * 64 + fo] = __float2half(fmaxf(a, 0.0f) * sdn[nd2]);
        }
    }
}

// ---- layer 3: fp16 gather (width 64 halves, 8 lanes/node x 16B) + segmented mean-pool ----

__global__ void agg64pool_kernel(const float4* __restrict__ hp, const float* __restrict__ dis,
                                 const int* __restrict__ excl, const int* __restrict__ psum,
                                 const int* __restrict__ esrc, const int* __restrict__ batch,
                                 float* __restrict__ pooled, int n, int Etot) {
    __shared__ float srow[32 * 64];
    int nd = threadIdx.x >> 3, lane = threadIdx.x & 7;
    int base = blockIdx.x * 32;
    int node = base + nd;
    if (node < n) {
        int s0 = offs_of(excl, psum, node);
        int send = (node + 1 < n) ? offs_of(excl, psum, node + 1) : Etot;
        int c = send - s0;
        float accA[8] = {0, 0, 0, 0, 0, 0, 0, 0};
        float accB[8] = {0, 0, 0, 0, 0, 0, 0, 0};
        acc_add_h8(accA, hp[(size_t)node * 8 + lane]);
        int e = 0;
        for (; e + 4 <= c; e += 4) {
            int sa = esrc[s0 + e], sb = esrc[s0 + e + 1];
            int sc = esrc[s0 + e + 2], sd = esrc[s0 + e + 3];
            float4 va = hp[(size_t)sa * 8 + lane], vb = hp[(size_t)sb * 8 + lane];
            float4 vc = hp[(size_t)sc * 8 + lane], vd = hp[(size_t)sd * 8 + lane];
            acc_add_h8(accA, va); acc_add_h8(accB, vb);
            acc_add_h8(accA, vc); acc_add_h8(accB, vd);
        }
        for (; e < c; ++e) acc_add_h8(accA, hp[(size_t)esrc[s0 + e] * 8 + lane]);
        float dn = dis[node];
#pragma unroll
        for (int j = 0; j < 8; ++j) srow[nd * 64 + lane * 8 + j] = (accA[j] + accB[j]) * dn;
    } else {
#pragma unroll
        for (int j = 0; j < 8; ++j) srow[nd * 64 + lane * 8 + j] = 0.0f;
    }
    __syncthreads();

    // quarter q handles nodes q*8..q*8+7: register run over sorted batch, flush on change
    int fo = threadIdx.x & 63, q = threadIdx.x >> 6;
    float acc = 0.0f;
    int gcur = -1;
    for (int k = 0; k < 8; ++k) {
        int node2 = base + q * 8 + k;
        if (node2 >= n) break;
        int g = batch[node2];
        if (g != gcur) {
            if (gcur >= 0) atomicAdd(&pooled[(size_t)gcur * 64 + fo], acc);
            acc = 0.0f;
            gcur = g;
        }
        acc += srow[(q * 8 + k) * 64 + fo];
    }
    if (gcur >= 0) atomicAdd(&pooled[(size_t)gcur * 64 + fo], acc);
}

// ---- head per graph: p128=(pooled/c)@W3+b3; h64=relu(p128@fw1+fb1); out=h64@fw2+fb2 ----

__global__ void head_kernel(const float* __restrict__ pooled, const int* __restrict__ batch,
                            const float* __restrict__ W3, const float* __restrict__ b3,
                            const float* __restrict__ fw1, const float* __restrict__ fb1,
                            const float* __restrict__ fw2, const float* __restrict__ fb2,
                            float* __restrict__ out, int n) {
    int g = blockIdx.x;
    auto lb = [&](int key) {
        int lo = 0, hi = n;
        while (lo < hi) {
            int mid = (lo + hi) >> 1;
            if (batch[mid] < key) lo = mid + 1; else hi = mid;
        }
        return lo;
    };
    int lo = lb(g), hi = lb(g + 1);
    float c = (float)(hi - lo);
    float inv = (c > 0.0f) ? 1.0f / c : 0.0f;

    __shared__ float sp[64];
    __shared__ float p128[128];
    __shared__ float h64[64];
    int j = threadIdx.x;  // 0..127
    if (j < 64) sp[j] = pooled[(size_t)g * 64 + j] * inv;
    __syncthreads();
    {
        float a = (c > 0.0f) ? b3[j] : 0.0f;  // empty graph: reference pooled128 = 0
#pragma unroll
        for (int k = 0; k < 64; ++k) a += sp[k] * W3[k * 128 + j];
        p128[j] = a;
    }
    __syncthreads();
    if (j < 64) {
        float a = fb1[j];
#pragma unroll
        for (int k = 0; k < 128; ++k) a += p128[k] * fw1[k * 64 + j];
        h64[j] = fmaxf(a, 0.0f);
    }
    __syncthreads();
    if (j < TGT) {
        float a = fb2[j];
#pragma unroll
        for (int k = 0; k < 64; ++k) a += h64[k] * fw2[k * TGT + j];
        out[(size_t)g * TGT + j] = a;
    }
}

extern "C" void kernel_launch(void* const* d_in, const int* in_sizes, int n_in,
                              void* d_out, int out_size, void* d_ws, size_t ws_size,
                              hipStream_t stream) {
    const float* x = (const float*)d_in[0];
    const int* edge_index = (const int*)d_in[1];
    const int* batch = (const int*)d_in[2];
    const float* W1 = (const float*)d_in[3];
    const float* b1 = (const float*)d_in[4];
    const float* W2 = (const float*)d_in[5];
    const float* b2 = (const float*)d_in[6];
    const float* W3 = (const float*)d_in[7];
    const float* b3 = (const float*)d_in[8];
    const float* fw1 = (const float*)d_in[9];
    const float* fb1 = (const float*)d_in[10];
    const float* fw2 = (const float*)d_in[11];
    const float* fb2 = (const float*)d_in[12];
    float* out = (float*)d_out;

    const int N = in_sizes[2];
    const int E = in_sizes[1] / 2;
    const int* src = edge_index;
    const int* dst = edge_index + E;

    // workspace: [incnt N][pooled GG*64] zeroed together, then the rest
    int* incnt = (int*)d_ws;                        // N
    float* pooled = (float*)(incnt + N);            // GG*64
    int* excl = (int*)(pooled + GG * 64);           // N
    int* psum = excl + N;                           // 256
    int* esrc = psum + 256;                         // E
    float* dis = (float*)(esrc + E);                // N
    __half* hx = (__half*)(dis + N);                // N*16 halves
    __half* h1 = hx + (size_t)N * 16;               // N*32 halves
    __half* h2 = h1 + (size_t)N * 32;               // N*64 halves

    const int T = 256;
    auto cdiv = [](long long a, long long b) { return (int)((a + b - 1) / b); };
    const int nb1 = cdiv(N, 256);

    // ---- CSR build ----
    const int zero_ints = N + GG * 64;
    zero_kernel<<<cdiv(cdiv(zero_ints, 4), T), T, 0, stream>>>((int4*)d_ws, cdiv(zero_ints, 4));
    deg_count_kernel<<<cdiv(E, T), T, 0, stream>>>(dst, incnt, E);
    prep_kernel<<<cdiv((long long)N * 16, T), T, 0, stream>>>(incnt, x, dis, hx, excl, psum, N, nb1);
    scan2_kernel<<<1, 256, 0, stream>>>(psum, nb1);
    place_kernel<<<cdiv(E, T), T, 0, stream>>>(src, dst, excl, psum, incnt, esrc, E);

    // ---- layers ----
    aggemm1_kernel<<<cdiv(N, 64), T, 0, stream>>>(
        (const float2*)hx, dis, excl, psum, esrc, W1, b1, h1, N, E);
    aggemm2_kernel<<<cdiv(N, 64), T, 0, stream>>>(
        (const float4*)h1, dis, excl, psum, esrc, W2, b2, h2, N, E);
    agg64pool_kernel<<<cdiv(N, 32), T, 0, stream>>>(
        (const float4*)h2, dis, excl, psum, esrc, batch, pooled, N, E);
    head_kernel<<<GG, 128, 0, stream>>>(pooled, batch, W3, b3, fw1, fb1, fw2, fb2, out, N);
}